// Round 1
// baseline (318.035 us; speedup 1.0000x reference)
//
#include <hip/hip_runtime.h>
#include <hip/hip_fp16.h>

typedef _Float16 f16;
typedef _Float16 f16x8 __attribute__((ext_vector_type(8)));
typedef float    f32x4 __attribute__((ext_vector_type(4)));

// Problem constants
constexpr int TREES = 16;
constexpr int NNODE = 255;
constexpr int NLEAF = 256;
constexpr int NCLS  = 100;
constexpr int NCPAD = 112;            // 7 x 16 MFMA col tiles
constexpr int NB    = 8192;
constexpr int DF    = 1024;
constexpr int KTOT  = TREES * NLEAF;  // 4096, K of GEMM2

// workspace layout (in halves)
constexpr size_t XH_OFF = 0;                                   // [8192][1024] fp16
constexpr size_t WH_OFF = XH_OFF + (size_t)NB * DF;            // [16][256][1024] fp16 (row 255 zero)
constexpr size_t SD_OFF = WH_OFF + (size_t)TREES * 256 * DF;   // [112][4096] fp16 (transposed, scaled leaf dist)
constexpr size_t MU_OFF = SD_OFF + (size_t)NCPAD * KTOT;       // [8192][4096] fp16

__device__ __forceinline__ void gload_lds16(const f16* g, f16* l) {
  __builtin_amdgcn_global_load_lds(
      (const __attribute__((address_space(1))) void*)g,
      (__attribute__((address_space(3))) void*)l, 16, 0, 0);
}

// ---------------- prep kernels ----------------
__global__ void cvt_x_k(const float* __restrict__ x, f16* __restrict__ xh) {
  int i = blockIdx.x * 256 + threadIdx.x;        // 8 floats per thread
  const float4* s = (const float4*)x + (size_t)i * 2;
  float4 u = s[0], v = s[1];
  f16x8 h = {(f16)u.x, (f16)u.y, (f16)u.z, (f16)u.w,
             (f16)v.x, (f16)v.y, (f16)v.z, (f16)v.w};
  *((f16x8*)xh + i) = h;
}

__global__ void cvt_w_k(const float* __restrict__ w, f16* __restrict__ wh) {
  int i = blockIdx.x * 256 + threadIdx.x;        // 8 halves per thread
  int flat = i * 8;
  int t = flat >> 18;
  int r = (flat >> 10) & 255;
  int k = flat & 1023;
  f16x8 h;
  if (r < NNODE) {
    const float4* s = (const float4*)(w + ((size_t)(t * NNODE + r) * DF + k));
    float4 u = s[0], v = s[1];
    h = (f16x8){(f16)u.x, (f16)u.y, (f16)u.z, (f16)u.w,
                (f16)v.x, (f16)v.y, (f16)v.z, (f16)v.w};
  } else {
    h = (f16x8){(f16)0.f, (f16)0.f, (f16)0.f, (f16)0.f,
                (f16)0.f, (f16)0.f, (f16)0.f, (f16)0.f};
  }
  *((f16x8*)wh + i) = h;
}

// leaf softmax * softmax(tree_weights), written transposed: sdt[c][t*256+l]
__global__ void prep_sdist_k(const float* __restrict__ ll,
                             const float* __restrict__ twin,
                             f16* __restrict__ sdt) {
  int id = blockIdx.x * 64 + threadIdx.x;        // 0..4095 = t*256 + l
  int t = id >> 8;
  float wm = -1e30f;
#pragma unroll
  for (int i = 0; i < 16; ++i) wm = fmaxf(wm, twin[i]);
  float wsum = 0.f;
#pragma unroll
  for (int i = 0; i < 16; ++i) wsum += __expf(twin[i] - wm);
  float wt = __expf(twin[t] - wm) / wsum;

  const float* rowp = ll + (size_t)id * NCLS;
  float mx = -1e30f;
  for (int c = 0; c < NCLS; c += 4) {
    float4 v = *(const float4*)(rowp + c);
    mx = fmaxf(fmaxf(fmaxf(mx, v.x), v.y), fmaxf(v.z, v.w));
  }
  float s = 0.f;
  for (int c = 0; c < NCLS; c += 4) {
    float4 v = *(const float4*)(rowp + c);
    s += __expf(v.x - mx) + __expf(v.y - mx) + __expf(v.z - mx) + __expf(v.w - mx);
  }
  float inv = wt / s;
  for (int c = 0; c < NCLS; ++c)
    sdt[(size_t)c * KTOT + id] = (f16)(__expf(rowp[c] - mx) * inv);
  for (int c = NCLS; c < NCPAD; ++c)
    sdt[(size_t)c * KTOT + id] = (f16)0.f;
}

// ---------------- GEMM1 + sigmoid + mu ----------------
// grid 2048 = 16 trees * 128 batch-blocks; block = 256 thr (4 waves, wave tile 64x64)
// tile: BM=64 rows x BN=256 nodes, BK=64, fp16 MFMA 16x16x32, double-buffered LDS.
__global__ __launch_bounds__(256, 2) void tree_gemm1(
    const f16* __restrict__ xh, const f16* __restrict__ wh,
    const float* __restrict__ bias, f16* __restrict__ muh) {
  __shared__ f16 smem[40960];  // 80 KiB: buf0 A(4096h)+B(16384h), buf1 same
  f16* A0 = smem;
  f16* B0 = smem + 4096;
  f16* A1 = smem + 20480;
  f16* B1 = smem + 24576;

  const int tid  = threadIdx.x;
  const int lane = tid & 63;
  const int wid  = tid >> 6;
  const int l15  = lane & 15;
  const int lq   = lane >> 4;

  // XCD-aware decode: xcd = t&7 so each XCD's L2 holds 2 trees' weights
  int bid  = blockIdx.x;
  int xcd  = bid & 7;
  int j    = bid >> 3;
  int brow = j & 127;
  int t    = ((j >> 7) << 3) | xcd;

  const f16* xsrc = xh + (size_t)brow * 64 * DF;
  const f16* wsrc = wh + (size_t)t * 256 * DF;

  // stage one K-tile (BK=64) with pre-swizzled global source addresses.
  // LDS element (row, kk): byte = (row*128 + kk*2) ^ ((row&7)<<4)
  auto stage = [&](int kt, f16* Ab, f16* Bb) {
    const f16* xk = xsrc + kt * 64;
    const f16* wk = wsrc + kt * 64;
#pragma unroll
    for (int ld = 0; ld < 2; ++ld) {           // A: 512 x 16B chunks
      int q  = ld * 256 + tid;
      int r  = q >> 3;
      int c0 = (q & 7) ^ (r & 7);
      gload_lds16(xk + (size_t)r * DF + c0 * 8, Ab + q * 8);
    }
#pragma unroll
    for (int ld = 0; ld < 8; ++ld) {           // B: 2048 x 16B chunks
      int q  = ld * 256 + tid;
      int n  = q >> 3;
      int c0 = (q & 7) ^ (n & 7);
      gload_lds16(wk + (size_t)n * DF + c0 * 8, Bb + q * 8);
    }
  };

  f32x4 acc[4][4];
#pragma unroll
  for (int m = 0; m < 4; ++m)
#pragma unroll
    for (int n = 0; n < 4; ++n) acc[m][n] = (f32x4){0.f, 0.f, 0.f, 0.f};

  auto compute = [&](const f16* Ab, const f16* Bb) {
#pragma unroll
    for (int s = 0; s < 2; ++s) {              // two K=32 slices per BK=64
      f16x8 af[4], bf[4];
#pragma unroll
      for (int m = 0; m < 4; ++m) {
        int r = m * 16 + l15;
        int byteoff = (r * 128 + s * 64 + lq * 16) ^ ((r & 7) << 4);
        af[m] = *(const f16x8*)((const char*)Ab + byteoff);
      }
#pragma unroll
      for (int n = 0; n < 4; ++n) {
        int node = wid * 64 + n * 16 + l15;
        int byteoff = (node * 128 + s * 64 + lq * 16) ^ ((node & 7) << 4);
        bf[n] = *(const f16x8*)((const char*)Bb + byteoff);
      }
#pragma unroll
      for (int m = 0; m < 4; ++m)
#pragma unroll
        for (int n = 0; n < 4; ++n)
          acc[m][n] = __builtin_amdgcn_mfma_f32_16x16x32_f16(af[m], bf[n], acc[m][n], 0, 0, 0);
    }
  };

  // 2-phase pipeline over 16 K-steps, manually 2x unrolled (static buffers)
  stage(0, A0, B0);
  __syncthreads();
  for (int kt = 0; kt < 14; kt += 2) {
    stage(kt + 1, A1, B1);
    compute(A0, B0);
    __syncthreads();
    stage(kt + 2, A0, B0);
    compute(A1, B1);
    __syncthreads();
  }
  stage(15, A1, B1);
  compute(A0, B0);
  __syncthreads();
  compute(A1, B1);

  // epilogue 1: bias + sigmoid -> p_lds (fp16, stride 258 to spread banks)
  f16* p_lds = smem;  // aliases buf0 (done with it); 64*258 = 16512 halves
#pragma unroll
  for (int m = 0; m < 4; ++m) {
#pragma unroll
    for (int n = 0; n < 4; ++n) {
      int col = wid * 64 + n * 16 + l15;
      float bv = (col < NNODE) ? bias[t * NNODE + col] : 0.f;
#pragma unroll
      for (int reg = 0; reg < 4; ++reg) {
        int row = m * 16 + lq * 4 + reg;
        float z = acc[m][n][reg] + bv;
        float p = 1.f / (1.f + __expf(-z));
        p_lds[row * 258 + col] = (f16)p;
      }
    }
  }
  __syncthreads();

  // epilogue 2: tree-doubling mu. thread -> (row = tid>>2, 64-leaf chunk = tid&3)
  int row   = tid >> 2;
  int chunk = tid & 3;
  const f16* P = p_lds + row * 258;
  float p0 = (float)P[0];
  float p1 = (float)P[1 + (chunk >> 1)];
  float pr = ((chunk >> 1) ? p0 : 1.f - p0) * ((chunk & 1) ? p1 : 1.f - p1);
  float p2 = (float)P[3 + chunk];
  float cur[64];
  {
    float mp = pr * p2;
    cur[1] = mp;
    cur[0] = pr - mp;
  }
#pragma unroll
  for (int d = 3; d <= 7; ++d) {
    int s  = 1 << (d - 2);
    int nb = (1 << d) - 1 + (chunk << (d - 2));
#pragma unroll
    for (int i = s - 1; i >= 0; --i) {
      float p  = (float)P[nb + i];
      float m  = cur[i];
      float mp = m * p;
      cur[2 * i + 1] = mp;
      cur[2 * i]     = m - mp;
    }
  }
  f16* dst = muh + (size_t)(brow * 64 + row) * KTOT + t * 256 + chunk * 64;
#pragma unroll
  for (int g = 0; g < 8; ++g) {
    f16x8 v;
#pragma unroll
    for (int jj = 0; jj < 8; ++jj) v[jj] = (f16)cur[g * 8 + jj];
    *(f16x8*)(dst + g * 8) = v;
  }
}

// ---------------- GEMM2: out = mu @ sdist (K-split, atomic) ----------------
// grid (128, 8): 128 row-blocks of 64 x 8 K-chunks of 512; 4 waves x 16 rows
__global__ __launch_bounds__(256, 4) void tree_gemm2(
    const f16* __restrict__ muh, const f16* __restrict__ sdt,
    float* __restrict__ out) {
  const int lane = threadIdx.x & 63;
  const int wid  = threadIdx.x >> 6;
  const int l15  = lane & 15;
  const int lq   = lane >> 4;
  const int mbase = blockIdx.x * 64 + wid * 16;
  const int k0    = blockIdx.y * 512 + lq * 8;

  const f16* arow = muh + (size_t)(mbase + l15) * KTOT;
  f32x4 acc[7];
#pragma unroll
  for (int n = 0; n < 7; ++n) acc[n] = (f32x4){0.f, 0.f, 0.f, 0.f};

#pragma unroll 2
  for (int kk = 0; kk < 512; kk += 32) {
    int kh = k0 + kk;
    f16x8 a = *(const f16x8*)(arow + kh);
#pragma unroll
    for (int n = 0; n < 7; ++n) {
      f16x8 b = *(const f16x8*)(sdt + (size_t)(n * 16 + l15) * KTOT + kh);
      acc[n] = __builtin_amdgcn_mfma_f32_16x16x32_f16(a, b, acc[n], 0, 0, 0);
    }
  }
#pragma unroll
  for (int n = 0; n < 7; ++n) {
    int c = n * 16 + l15;
    if (c < NCLS) {
#pragma unroll
      for (int reg = 0; reg < 4; ++reg) {
        int r = mbase + lq * 4 + reg;
        atomicAdd(out + (size_t)r * NCLS + c, acc[n][reg]);
      }
    }
  }
}

// ---------------- launch ----------------
extern "C" void kernel_launch(void* const* d_in, const int* in_sizes, int n_in,
                              void* d_out, int out_size, void* d_ws, size_t ws_size,
                              hipStream_t stream) {
  const float* x  = (const float*)d_in[0];
  const float* sw = (const float*)d_in[1];
  const float* sb = (const float*)d_in[2];
  const float* ll = (const float*)d_in[3];
  const float* tw = (const float*)d_in[4];
  float* out = (float*)d_out;

  f16* ws  = (f16*)d_ws;
  f16* xh  = ws + XH_OFF;
  f16* wh  = ws + WH_OFF;
  f16* sdt = ws + SD_OFF;
  f16* muh = ws + MU_OFF;

  hipMemsetAsync(d_out, 0, (size_t)out_size * sizeof(float), stream);
  cvt_x_k<<<(NB * DF / 8) / 256, 256, 0, stream>>>(x, xh);
  cvt_w_k<<<(TREES * 256 * DF / 8) / 256, 256, 0, stream>>>(sw, wh);
  prep_sdist_k<<<64, 64, 0, stream>>>(ll, tw, sdt);
  tree_gemm1<<<TREES * (NB / 64), 256, 0, stream>>>(xh, wh, sb, muh);
  tree_gemm2<<<dim3(NB / 64, 8), 256, 0, stream>>>(muh, sdt, out);
}

// Round 2
// 218.079 us; speedup vs baseline: 1.4583x; 1.4583x over previous
//
#include <hip/hip_runtime.h>
#include <hip/hip_fp16.h>

typedef _Float16 f16;
typedef _Float16 f16x8 __attribute__((ext_vector_type(8)));
typedef float    f32x4 __attribute__((ext_vector_type(4)));

// Problem constants
constexpr int TREES = 16;
constexpr int NNODE = 255;
constexpr int NLEAF = 256;
constexpr int NCLS  = 100;
constexpr int NCPAD = 112;            // 7 x 16 MFMA col tiles
constexpr int NB    = 8192;
constexpr int DF    = 1024;
constexpr int KTOT  = TREES * NLEAF;  // 4096

// workspace layout
constexpr size_t XH_OFF = 0;                                   // [8192][1024] fp16
constexpr size_t WH_OFF = XH_OFF + (size_t)NB * DF;            // [16][256][1024] fp16 (row 255 zero)
constexpr size_t SD_OFF = WH_OFF + (size_t)TREES * 256 * DF;   // [112][4096] fp16 (transposed, scaled leaf dist)
constexpr size_t PT_OFF_F = (SD_OFF + (size_t)NCPAD * KTOT) / 2;  // float offset: [16][8192][100] f32 partials

__device__ __forceinline__ void gload_lds16(const f16* g, f16* l) {
  __builtin_amdgcn_global_load_lds(
      (const __attribute__((address_space(1))) void*)g,
      (__attribute__((address_space(3))) void*)l, 16, 0, 0);
}

// ---------------- prep kernels ----------------
__global__ void cvt_x_k(const float* __restrict__ x, f16* __restrict__ xh) {
  int i = blockIdx.x * 256 + threadIdx.x;        // 8 floats per thread
  const float4* s = (const float4*)x + (size_t)i * 2;
  float4 u = s[0], v = s[1];
  f16x8 h = {(f16)u.x, (f16)u.y, (f16)u.z, (f16)u.w,
             (f16)v.x, (f16)v.y, (f16)v.z, (f16)v.w};
  *((f16x8*)xh + i) = h;
}

__global__ void cvt_w_k(const float* __restrict__ w, f16* __restrict__ wh) {
  int i = blockIdx.x * 256 + threadIdx.x;        // 8 halves per thread
  int flat = i * 8;
  int t = flat >> 18;
  int r = (flat >> 10) & 255;
  int k = flat & 1023;
  f16x8 h;
  if (r < NNODE) {
    const float4* s = (const float4*)(w + ((size_t)(t * NNODE + r) * DF + k));
    float4 u = s[0], v = s[1];
    h = (f16x8){(f16)u.x, (f16)u.y, (f16)u.z, (f16)u.w,
                (f16)v.x, (f16)v.y, (f16)v.z, (f16)v.w};
  } else {
    h = (f16x8){(f16)0.f, (f16)0.f, (f16)0.f, (f16)0.f,
                (f16)0.f, (f16)0.f, (f16)0.f, (f16)0.f};
  }
  *((f16x8*)wh + i) = h;
}

// leaf softmax * softmax(tree_weights), written transposed: sdt[c][t*256+l]
__global__ void prep_sdist_k(const float* __restrict__ ll,
                             const float* __restrict__ twin,
                             f16* __restrict__ sdt) {
  int id = blockIdx.x * 64 + threadIdx.x;        // 0..4095 = t*256 + l
  int t = id >> 8;
  float wm = -1e30f;
#pragma unroll
  for (int i = 0; i < 16; ++i) wm = fmaxf(wm, twin[i]);
  float wsum = 0.f;
#pragma unroll
  for (int i = 0; i < 16; ++i) wsum += __expf(twin[i] - wm);
  float wt = __expf(twin[t] - wm) / wsum;

  const float* rowp = ll + (size_t)id * NCLS;
  float mx = -1e30f;
  for (int c = 0; c < NCLS; c += 4) {
    float4 v = *(const float4*)(rowp + c);
    mx = fmaxf(fmaxf(fmaxf(mx, v.x), v.y), fmaxf(v.z, v.w));
  }
  float s = 0.f;
  for (int c = 0; c < NCLS; c += 4) {
    float4 v = *(const float4*)(rowp + c);
    s += __expf(v.x - mx) + __expf(v.y - mx) + __expf(v.z - mx) + __expf(v.w - mx);
  }
  float inv = wt / s;
  for (int c = 0; c < NCLS; ++c)
    sdt[(size_t)c * KTOT + id] = (f16)(__expf(rowp[c] - mx) * inv);
  for (int c = NCLS; c < NCPAD; ++c)
    sdt[(size_t)c * KTOT + id] = (f16)0.f;
}

// ---------------- fused GEMM1 + sigmoid + mu + leaf-GEMM ----------------
// grid 2048 = 16 trees * 128 batch-blocks; block = 256 thr (4 waves)
// main loop: BM=64 x BN=256 nodes, BK=64, fp16 MFMA 16x16x32, double-buffered LDS.
// epilogue: mu(64x256) @ sdt_t(256x112) in-block, partials -> ws (no atomics).
__global__ __launch_bounds__(256, 2) void tree_gemm1(
    const f16* __restrict__ xh, const f16* __restrict__ wh,
    const float* __restrict__ bias, const f16* __restrict__ sdt,
    float* __restrict__ ptree) {
  __shared__ f16 smem[40960];  // 80 KiB
  f16* A0 = smem;
  f16* B0 = smem + 4096;
  f16* A1 = smem + 20480;
  f16* B1 = smem + 24576;

  const int tid  = threadIdx.x;
  const int lane = tid & 63;
  const int wid  = tid >> 6;
  const int l15  = lane & 15;
  const int lq   = lane >> 4;

  // XCD-aware decode: xcd = t&7 so each XCD's L2 holds 2 trees' weights
  int bid  = blockIdx.x;
  int xcd  = bid & 7;
  int j    = bid >> 3;
  int brow = j & 127;
  int t    = ((j >> 7) << 3) | xcd;

  const f16* xsrc = xh + (size_t)brow * 64 * DF;
  const f16* wsrc = wh + (size_t)t * 256 * DF;

  // stage one K-tile (BK=64) with pre-swizzled global source addresses.
  // LDS element (row, kk): byte = (row*128 + kk*2) ^ ((row&7)<<4)
  auto stage = [&](int kt, f16* Ab, f16* Bb) {
    const f16* xk = xsrc + kt * 64;
    const f16* wk = wsrc + kt * 64;
#pragma unroll
    for (int ld = 0; ld < 2; ++ld) {           // A: 512 x 16B chunks
      int q  = ld * 256 + tid;
      int r  = q >> 3;
      int c0 = (q & 7) ^ (r & 7);
      gload_lds16(xk + (size_t)r * DF + c0 * 8, Ab + q * 8);
    }
#pragma unroll
    for (int ld = 0; ld < 8; ++ld) {           // B: 2048 x 16B chunks
      int q  = ld * 256 + tid;
      int n  = q >> 3;
      int c0 = (q & 7) ^ (n & 7);
      gload_lds16(wk + (size_t)n * DF + c0 * 8, Bb + q * 8);
    }
  };

  f32x4 acc[4][4];
#pragma unroll
  for (int m = 0; m < 4; ++m)
#pragma unroll
    for (int n = 0; n < 4; ++n) acc[m][n] = (f32x4){0.f, 0.f, 0.f, 0.f};

  auto compute = [&](const f16* Ab, const f16* Bb) {
#pragma unroll
    for (int s = 0; s < 2; ++s) {              // two K=32 slices per BK=64
      f16x8 af[4], bf[4];
#pragma unroll
      for (int m = 0; m < 4; ++m) {
        int r = m * 16 + l15;
        int byteoff = (r * 128 + s * 64 + lq * 16) ^ ((r & 7) << 4);
        af[m] = *(const f16x8*)((const char*)Ab + byteoff);
      }
#pragma unroll
      for (int n = 0; n < 4; ++n) {
        int node = wid * 64 + n * 16 + l15;
        int byteoff = (node * 128 + s * 64 + lq * 16) ^ ((node & 7) << 4);
        bf[n] = *(const f16x8*)((const char*)Bb + byteoff);
      }
#pragma unroll
      for (int m = 0; m < 4; ++m)
#pragma unroll
        for (int n = 0; n < 4; ++n)
          acc[m][n] = __builtin_amdgcn_mfma_f32_16x16x32_f16(af[m], bf[n], acc[m][n], 0, 0, 0);
    }
  };

  // 2-phase pipeline over 16 K-steps
  stage(0, A0, B0);
  __syncthreads();
  for (int kt = 0; kt < 14; kt += 2) {
    stage(kt + 1, A1, B1);
    compute(A0, B0);
    __syncthreads();
    stage(kt + 2, A0, B0);
    compute(A1, B1);
    __syncthreads();
  }
  stage(15, A1, B1);
  compute(A0, B0);
  __syncthreads();
  compute(A1, B1);

  // epilogue 1: bias + sigmoid -> p_lds (fp16, stride 258)
  f16* p_lds = smem;  // bytes 0..33024 (aliases A0/B0 region; A1/B1 untouched)
#pragma unroll
  for (int m = 0; m < 4; ++m) {
#pragma unroll
    for (int n = 0; n < 4; ++n) {
      int col = wid * 64 + n * 16 + l15;
      float bv = (col < NNODE) ? bias[t * NNODE + col] : 0.f;
#pragma unroll
      for (int reg = 0; reg < 4; ++reg) {
        int row = m * 16 + lq * 4 + reg;
        float z = acc[m][n][reg] + bv;
        float p = 1.f / (1.f + __expf(-z));
        p_lds[row * 258 + col] = (f16)p;
      }
    }
  }
  __syncthreads();

  // epilogue 2: tree-doubling mu in registers. thread -> (row = tid>>2, chunk = tid&3)
  int row   = tid >> 2;
  int chunk = tid & 3;
  const f16* P = p_lds + row * 258;
  float p0 = (float)P[0];
  float p1 = (float)P[1 + (chunk >> 1)];
  float pr = ((chunk >> 1) ? p0 : 1.f - p0) * ((chunk & 1) ? p1 : 1.f - p1);
  float p2 = (float)P[3 + chunk];
  float cur[64];
  {
    float mp = pr * p2;
    cur[1] = mp;
    cur[0] = pr - mp;
  }
#pragma unroll
  for (int d = 3; d <= 7; ++d) {
    int s  = 1 << (d - 2);
    int nb = (1 << d) - 1 + (chunk << (d - 2));
#pragma unroll
    for (int i = s - 1; i >= 0; --i) {
      float p  = (float)P[nb + i];
      float m  = cur[i];
      float mp = m * p;
      cur[2 * i + 1] = mp;
      cur[2 * i]     = m - mp;
    }
  }

  // write mu -> LDS [64][256] f16, XOR-swizzled (row&7)<<4 on byte offset
  char* mub = (char*)(smem + 18432);   // bytes 36864..69632 (disjoint from p_lds)
#pragma unroll
  for (int g = 0; g < 8; ++g) {
    f16x8 v;
#pragma unroll
    for (int jj = 0; jj < 8; ++jj) v[jj] = (f16)cur[g * 8 + jj];
    int byteoff = (row * 512 + chunk * 128 + g * 16) ^ ((row & 7) << 4);
    *(f16x8*)(mub + byteoff) = v;
  }
  __syncthreads();   // p_lds reads done; mu visible

  // epilogue 3: out_tile(64x112) = mu(64x256) @ sdt_t(112x256), K=256.
  // sdt slice staged in 2 chunks (64 + 48 rows) into bytes 0.. (over p_lds).
  char* sdb = (char*)smem;
  auto stage_sdt = [&](int c0, int nrows) {
    int nchunks = nrows * 32;                   // 32 x 16B per 512B row
    for (int q = tid; q < nchunks; q += 256) {
      int r = q >> 5;
      int jj = q & 31;
      const f16* src = sdt + (size_t)(c0 + r) * KTOT + t * 256 + ((jj * 8) ^ ((r & 7) << 3));
      gload_lds16(src, smem + q * 8);
    }
  };

  f32x4 acc2[7];
#pragma unroll
  for (int n = 0; n < 7; ++n) acc2[n] = (f32x4){0.f, 0.f, 0.f, 0.f};

  int arow = wid * 16 + l15;
  stage_sdt(0, 64);
  __syncthreads();
#pragma unroll
  for (int n = 0; n < 4; ++n) {
#pragma unroll
    for (int s = 0; s < 8; ++s) {
      int abyte = (arow * 512 + s * 64 + lq * 16) ^ ((arow & 7) << 4);
      f16x8 a = *(const f16x8*)(mub + abyte);
      int br = n * 16 + l15;
      int bbyte = (br * 512 + s * 64 + lq * 16) ^ ((br & 7) << 4);
      f16x8 b = *(const f16x8*)(sdb + bbyte);
      acc2[n] = __builtin_amdgcn_mfma_f32_16x16x32_f16(a, b, acc2[n], 0, 0, 0);
    }
  }
  __syncthreads();
  stage_sdt(64, 48);
  __syncthreads();
#pragma unroll
  for (int n = 4; n < 7; ++n) {
#pragma unroll
    for (int s = 0; s < 8; ++s) {
      int abyte = (arow * 512 + s * 64 + lq * 16) ^ ((arow & 7) << 4);
      f16x8 a = *(const f16x8*)(mub + abyte);
      int br = (n - 4) * 16 + l15;
      int bbyte = (br * 512 + s * 64 + lq * 16) ^ ((br & 7) << 4);
      f16x8 b = *(const f16x8*)(sdb + bbyte);
      acc2[n] = __builtin_amdgcn_mfma_f32_16x16x32_f16(a, b, acc2[n], 0, 0, 0);
    }
  }

  // store per-tree partials (no atomics): ptree[t][brow*64 + r][c]
  float* pt = ptree + ((size_t)t * NB + brow * 64) * NCLS;
#pragma unroll
  for (int n = 0; n < 7; ++n) {
    int col = n * 16 + l15;
    if (col < NCLS) {
#pragma unroll
      for (int reg = 0; reg < 4; ++reg) {
        int r = wid * 16 + lq * 4 + reg;
        pt[(size_t)r * NCLS + col] = acc2[n][reg];
      }
    }
  }
}

// ---------------- reduce over trees ----------------
__global__ void reduce_k(const float* __restrict__ pt, float* __restrict__ out) {
  int i = blockIdx.x * 256 + threadIdx.x;        // float4 index; 204800 total
  constexpr size_t STRIDE4 = (size_t)NB * NCLS / 4;
  const float4* p = (const float4*)pt + i;
  float4 s = p[0];
#pragma unroll
  for (int t = 1; t < TREES; ++t) {
    float4 v = p[t * STRIDE4];
    s.x += v.x; s.y += v.y; s.z += v.z; s.w += v.w;
  }
  ((float4*)out)[i] = s;
}

// ---------------- launch ----------------
extern "C" void kernel_launch(void* const* d_in, const int* in_sizes, int n_in,
                              void* d_out, int out_size, void* d_ws, size_t ws_size,
                              hipStream_t stream) {
  const float* x  = (const float*)d_in[0];
  const float* sw = (const float*)d_in[1];
  const float* sb = (const float*)d_in[2];
  const float* ll = (const float*)d_in[3];
  const float* tw = (const float*)d_in[4];
  float* out = (float*)d_out;

  f16* ws  = (f16*)d_ws;
  f16* xh  = ws + XH_OFF;
  f16* wh  = ws + WH_OFF;
  f16* sdt = ws + SD_OFF;
  float* ptree = (float*)d_ws + PT_OFF_F;

  cvt_x_k<<<(NB * DF / 8) / 256, 256, 0, stream>>>(x, xh);
  cvt_w_k<<<(TREES * 256 * DF / 8) / 256, 256, 0, stream>>>(sw, wh);
  prep_sdist_k<<<64, 64, 0, stream>>>(ll, tw, sdt);
  tree_gemm1<<<TREES * (NB / 64), 256, 0, stream>>>(xh, wh, sb, sdt, ptree);
  reduce_k<<<(NB * NCLS / 4) / 256, 256, 0, stream>>>(ptree, out);
}